// Round 8
// baseline (1267.151 us; speedup 1.0000x reference)
//
#include <hip/hip_runtime.h>
#include <cstdint>
#include <cstddef>

#define T_STEPS 200
#define B_SZ    256
#define I_SZ    784
#define H_SZ    1000
#define O_SZ    10
#define M_ROWS  (T_STEPS * B_SZ)   // 51200

#define KT        25               // K padded 784 -> 800, 25 tiles of 32
#define TILE_WORDS 4096            // 32 k x 128 cols (floats)
#define MBLKS     400
#define NBLKS     8

// granule (4-float) swizzle within a 128-word k-row; inverse for pack.
__device__ __forceinline__ int swz32(int g) { return (g & 24) | ((g + (g >> 3)) & 7); }
__device__ __forceinline__ int inv32(int p) { return (p & 24) | ((p - (p >> 3)) & 7); }

typedef const __attribute__((address_space(1))) void gvoid;
typedef __attribute__((address_space(3))) void lvoid;
__device__ __forceinline__ void gload16(const void* g, void* l) {
    __builtin_amdgcn_global_load_lds((gvoid*)g, (lvoid*)l, 16, 0, 0);
}

// ---------------------------------------------------------------------------
// pack: src [nrows x 784] row-major -> dst [blk][kt][k_local 32][128 words,
// granule g at position swz32(g)], zero-filled for row >= nrows or k >= 784.
// ---------------------------------------------------------------------------
__global__ __launch_bounds__(256) void pack_kernel(
    const float* __restrict__ src, float* __restrict__ dst, int nrows)
{
    int bid = blockIdx.x;
    int blk = bid / KT, kt = bid - blk * KT;

    __shared__ float T[32 * 132];
    const int tid = threadIdx.x;

    #pragma unroll
    for (int it = 0; it < 4; ++it) {
        int id = tid + it * 256;        // 0..1023
        int r  = id >> 3;               // 0..127
        int c4 = id & 7;                // 0..7
        int row = blk * 128 + r;
        int k   = kt * 32 + c4 * 4;
        float4 v = make_float4(0.f, 0.f, 0.f, 0.f);
        if (row < nrows && k < I_SZ)
            v = *(const float4*)(src + (size_t)row * I_SZ + k);
        T[(c4*4 + 0) * 132 + r] = v.x;
        T[(c4*4 + 1) * 132 + r] = v.y;
        T[(c4*4 + 2) * 132 + r] = v.z;
        T[(c4*4 + 3) * 132 + r] = v.w;
    }
    __syncthreads();

    float* out = dst + (size_t)(blk * KT + kt) * TILE_WORDS;
    #pragma unroll
    for (int it = 0; it < 4; ++it) {
        int id = tid + it * 256;
        int k  = id >> 5;               // 0..31
        int pg = id & 31;               // output granule position
        int g  = inv32(pg);             // source granule
        float4 v = *(const float4*)&T[k * 132 + g * 4];
        *(float4*)(out + k * 128 + pg * 4) = v;   // coalesced
    }
}

// ---------------------------------------------------------------------------
// GEMM1 v4: fp32 VALU, 128x128 tile, 8x8/thread, BK=32.
// 2-phase pipeline: STAGE(kt+1) issued BEFORE compute(kt); double-buffered
// LDS (64 KB); ONE __syncthreads per kt (its vmcnt/lgkm drain covers the
// staged loads, issued a full compute-phase earlier).
// Full k-unroll: all ds_read offsets fold into immediates (zero addr VALU).
// ---------------------------------------------------------------------------
__global__ __launch_bounds__(256, 2) void gemm1_v4(
    const float* __restrict__ Xp, const float* __restrict__ Wp,
    const float* __restrict__ b_ih, const float* __restrict__ b_hh,
    float* __restrict__ Z)
{
    __shared__ float Al[2][TILE_WORDS];   // 32 KB
    __shared__ float Bl[2][TILE_WORDS];   // 32 KB

    const int tid = threadIdx.x;
    const int tr  = tid >> 4;          // 0..15
    const int tc  = tid & 15;          // 0..15

    // XCD-bijective swizzle: 3200 = 8 * 400 (divisible -> simple form OK)
    int bid  = blockIdx.x;
    int wg   = (bid & 7) * 400 + (bid >> 3);
    int mblk = wg >> 3;                // 0..399
    int nblk = wg & 7;                 // 0..7
    const int row0 = mblk * 128;
    const int col0 = nblk * 128;

    const int a0 = swz32(2*tr)     * 4;
    const int a1 = swz32(2*tr + 1) * 4;
    const int b0 = swz32(2*tc)     * 4;
    const int b1 = swz32(2*tc + 1) * 4;

    const float* pA = Xp + (size_t)mblk * KT * TILE_WORDS;
    const float* pB = Wp + (size_t)nblk * KT * TILE_WORDS;

    float acc[8][8] = {};

    // stage kt into buffer b
    auto stage = [&](int kt, int b) {
        const float* sA = pA + kt * TILE_WORDS + tid * 4;
        const float* sB = pB + kt * TILE_WORDS + tid * 4;
        gload16(sA,        &Al[b][        tid * 4]);
        gload16(sA + 1024, &Al[b][1024 + tid * 4]);
        gload16(sA + 2048, &Al[b][2048 + tid * 4]);
        gload16(sA + 3072, &Al[b][3072 + tid * 4]);
        gload16(sB,        &Bl[b][        tid * 4]);
        gload16(sB + 1024, &Bl[b][1024 + tid * 4]);
        gload16(sB + 2048, &Bl[b][2048 + tid * 4]);
        gload16(sB + 3072, &Bl[b][3072 + tid * 4]);
    };

    stage(0, 0);
    __syncthreads();                   // drain prologue stage

    for (int kt = 0; kt < KT; ++kt) {
        const int cur = kt & 1;
        if (kt + 1 < KT) stage(kt + 1, cur ^ 1);   // overlap with compute

        const float* A = Al[cur];
        const float* B = Bl[cur];

        #pragma unroll
        for (int k = 0; k < 32; ++k) {
            const float4 A0 = *(const float4*)&A[k*128 + a0];
            const float4 A1 = *(const float4*)&A[k*128 + a1];
            const float4 B0 = *(const float4*)&B[k*128 + b0];
            const float4 B1 = *(const float4*)&B[k*128 + b1];
            #define FMA_ROW(i, av) \
                acc[i][0] = fmaf(av, B0.x, acc[i][0]); \
                acc[i][1] = fmaf(av, B0.y, acc[i][1]); \
                acc[i][2] = fmaf(av, B0.z, acc[i][2]); \
                acc[i][3] = fmaf(av, B0.w, acc[i][3]); \
                acc[i][4] = fmaf(av, B1.x, acc[i][4]); \
                acc[i][5] = fmaf(av, B1.y, acc[i][5]); \
                acc[i][6] = fmaf(av, B1.z, acc[i][6]); \
                acc[i][7] = fmaf(av, B1.w, acc[i][7]);
            FMA_ROW(0, A0.x) FMA_ROW(1, A0.y) FMA_ROW(2, A0.z) FMA_ROW(3, A0.w)
            FMA_ROW(4, A1.x) FMA_ROW(5, A1.y) FMA_ROW(6, A1.z) FMA_ROW(7, A1.w)
            #undef FMA_ROW
        }
        __syncthreads();   // all waves done reading buf[cur]; staged loads drained
    }

    // ---- epilogue ----
    float bias[8];
    #pragma unroll
    for (int j = 0; j < 8; ++j) {
        int cc = col0 + tc * 8 + j;
        bias[j] = (cc < H_SZ) ? (b_ih[cc] + b_hh[cc]) : 0.f;
    }

    const bool full = (col0 + 127 < H_SZ);
    #pragma unroll
    for (int i = 0; i < 8; ++i) {
        int rr = row0 + tr * 8 + i;
        float* zrow = Z + (size_t)rr * H_SZ + col0 + tc * 8;
        if (full) {
            float4 v0 = make_float4(acc[i][0] + bias[0], acc[i][1] + bias[1],
                                    acc[i][2] + bias[2], acc[i][3] + bias[3]);
            float4 v1 = make_float4(acc[i][4] + bias[4], acc[i][5] + bias[5],
                                    acc[i][6] + bias[6], acc[i][7] + bias[7]);
            *(float4*)(zrow + 0) = v0;
            *(float4*)(zrow + 4) = v1;
        } else {
            #pragma unroll
            for (int j = 0; j < 8; ++j) {
                int cc = col0 + tc * 8 + j;
                if (cc < H_SZ) zrow[j] = acc[i][j] + bias[j];
            }
        }
    }
}

// ---------------------------------------------------------------------------
// Scan1: per (b,h) chain over t; in-place z1 -> spikes (0/1 as float).
// ---------------------------------------------------------------------------
__global__ __launch_bounds__(256) void scan1_kernel(
    float* __restrict__ Z, const float* __restrict__ beta)
{
    int idx = blockIdx.x * blockDim.x + threadIdx.x;
    if (idx >= B_SZ * H_SZ) return;
    int h = idx % H_SZ;
    float be = fminf(fmaxf(beta[h], 0.f), 1.f);
    float hm = 0.f;
    const size_t stride = (size_t)B_SZ * H_SZ;
    float* p = Z + idx;
    for (int t = 0; t < T_STEPS; ++t) {
        float v = p[(size_t)t * stride];
        hm = fmaxf(fmaf(be, hm, v), 0.f);
        p[(size_t)t * stride] = (hm > 1.0f) ? 1.0f : 0.0f;
    }
}

// ---------------------------------------------------------------------------
// GEMM2: one wave per row, W2 (40KB) in LDS. Writes directly to d_out.
// ---------------------------------------------------------------------------
__global__ __launch_bounds__(256) void gemm2_kernel(
    const float* __restrict__ S, const float* __restrict__ W2,
    const float* __restrict__ b_ih2, const float* __restrict__ b_hh2,
    float* __restrict__ Z2)
{
    __shared__ float W2s[O_SZ * H_SZ];
    for (int i = threadIdx.x; i < O_SZ * H_SZ; i += blockDim.x)
        W2s[i] = W2[i];
    __syncthreads();

    const int wave  = threadIdx.x >> 6;
    const int lane  = threadIdx.x & 63;
    const int wgid  = blockIdx.x * (blockDim.x >> 6) + wave;
    const int nwave = gridDim.x * (blockDim.x >> 6);

    for (int m = wgid; m < M_ROWS; m += nwave) {
        const float* row = S + (size_t)m * H_SZ;
        float acc[O_SZ];
        #pragma unroll
        for (int o = 0; o < O_SZ; ++o) acc[o] = 0.f;

        for (int h = lane; h < H_SZ; h += 64) {
            float s = row[h];
            #pragma unroll
            for (int o = 0; o < O_SZ; ++o)
                acc[o] = fmaf(s, W2s[o * H_SZ + h], acc[o]);
        }
        #pragma unroll
        for (int o = 0; o < O_SZ; ++o) {
            float v = acc[o];
            #pragma unroll
            for (int off = 32; off > 0; off >>= 1)
                v += __shfl_down(v, off, 64);
            if (lane == 0)
                Z2[(size_t)m * O_SZ + o] = v + b_ih2[o] + b_hh2[o];
        }
    }
}

// ---------------------------------------------------------------------------
// Scan2: in-place on d_out (thread-private read-then-write).
// ---------------------------------------------------------------------------
#define CH 20
__global__ __launch_bounds__(256) void scan2_kernel(
    float* __restrict__ Z2io, const float* __restrict__ beta2)
{
    int idx = blockIdx.x * blockDim.x + threadIdx.x;
    if (idx >= B_SZ * O_SZ) return;
    int o = idx % O_SZ;
    float be = fminf(fmaxf(beta2[o], 0.f), 1.f);
    float hm = 0.f;
    const int stride = B_SZ * O_SZ;
    for (int t0 = 0; t0 < T_STEPS; t0 += CH) {
        float v[CH];
        #pragma unroll
        for (int i = 0; i < CH; ++i)
            v[i] = Z2io[(size_t)(t0 + i) * stride + idx];
        #pragma unroll
        for (int i = 0; i < CH; ++i) {
            hm = fmaxf(fmaf(be, hm, v[i]), 0.f);
            Z2io[(size_t)(t0 + i) * stride + idx] = (hm > 1.0f) ? 1.0f : 0.0f;
        }
    }
}

// ---------------------------------------------------------------------------
extern "C" void kernel_launch(void* const* d_in, const int* in_sizes, int n_in,
                              void* d_out, int out_size, void* d_ws, size_t ws_size,
                              hipStream_t stream)
{
    const float* x     = (const float*)d_in[0];
    const float* W1    = (const float*)d_in[1];
    const float* bih1  = (const float*)d_in[2];
    const float* bhh1  = (const float*)d_in[3];
    const float* beta1 = (const float*)d_in[4];
    const float* W2    = (const float*)d_in[5];
    const float* bih2  = (const float*)d_in[6];
    const float* bhh2  = (const float*)d_in[7];
    const float* beta2 = (const float*)d_in[8];
    float* out = (float*)d_out;

    // workspace: z1 (204.8 MB) + Xp (163.84 MB) + Wp (3.28 MB) = 371.9 MB
    char* base = (char*)d_ws;
    float* z1 = (float*)base;
    float* Xp = (float*)(base + (size_t)M_ROWS * H_SZ * 4);
    float* Wp = Xp + (size_t)MBLKS * KT * TILE_WORDS;

    pack_kernel<<<MBLKS * KT, 256, 0, stream>>>(x,  Xp, M_ROWS);
    pack_kernel<<<NBLKS * KT, 256, 0, stream>>>(W1, Wp, H_SZ);

    gemm1_v4<<<MBLKS * NBLKS, 256, 0, stream>>>(Xp, Wp, bih1, bhh1, z1);

    scan1_kernel<<<(B_SZ * H_SZ) / 256, 256, 0, stream>>>(z1, beta1);
    gemm2_kernel<<<2048, 256, 0, stream>>>(z1, W2, bih2, bhh2, out);
    scan2_kernel<<<(B_SZ * O_SZ + 255) / 256, 256, 0, stream>>>(out, beta2);
}

// Round 9
// 1235.649 us; speedup vs baseline: 1.0255x; 1.0255x over previous
//
#include <hip/hip_runtime.h>
#include <cstdint>
#include <cstddef>

#define T_STEPS 200
#define B_SZ    256
#define I_SZ    784
#define H_SZ    1000
#define O_SZ    10
#define M_ROWS  (T_STEPS * B_SZ)   // 51200

#define KT        25               // K padded 784 -> 800, 25 tiles of 32
#define TILE_WORDS 4096            // 32 k x 128 cols (floats) per packed panel
#define MBLKS     400              // 128-row panels in Xp
#define NBLKS     8
#define MBLK2S    200              // 256-row block tiles

// granule (4-float) swizzle within a 128-word k-row; inverse for pack.
__device__ __forceinline__ int swz32(int g) { return (g & 24) | ((g + (g >> 3)) & 7); }
__device__ __forceinline__ int inv32(int p) { return (p & 24) | ((p - (p >> 3)) & 7); }

typedef const __attribute__((address_space(1))) void gvoid;
typedef __attribute__((address_space(3))) void lvoid;
__device__ __forceinline__ void gload16(const void* g, void* l) {
    __builtin_amdgcn_global_load_lds((gvoid*)g, (lvoid*)l, 16, 0, 0);
}

// ---------------------------------------------------------------------------
// pack: src [nrows x 784] row-major -> dst [blk128][kt][k_local 32][128 words,
// granule g stored at position swz32(g)], zero-filled outside.
// ---------------------------------------------------------------------------
__global__ __launch_bounds__(256) void pack_kernel(
    const float* __restrict__ src, float* __restrict__ dst, int nrows)
{
    int bid = blockIdx.x;
    int blk = bid / KT, kt = bid - blk * KT;

    __shared__ float T[32 * 132];
    const int tid = threadIdx.x;

    #pragma unroll
    for (int it = 0; it < 4; ++it) {
        int id = tid + it * 256;        // 0..1023
        int r  = id >> 3;               // 0..127
        int c4 = id & 7;                // 0..7
        int row = blk * 128 + r;
        int k   = kt * 32 + c4 * 4;
        float4 v = make_float4(0.f, 0.f, 0.f, 0.f);
        if (row < nrows && k < I_SZ)
            v = *(const float4*)(src + (size_t)row * I_SZ + k);
        T[(c4*4 + 0) * 132 + r] = v.x;
        T[(c4*4 + 1) * 132 + r] = v.y;
        T[(c4*4 + 2) * 132 + r] = v.z;
        T[(c4*4 + 3) * 132 + r] = v.w;
    }
    __syncthreads();

    float* out = dst + (size_t)(blk * KT + kt) * TILE_WORDS;
    #pragma unroll
    for (int it = 0; it < 4; ++it) {
        int id = tid + it * 256;
        int k  = id >> 5;               // 0..31
        int pg = id & 31;               // output granule position
        int g  = inv32(pg);             // source granule
        float4 v = *(const float4*)&T[k * 132 + g * 4];
        *(float4*)(out + k * 128 + pg * 4) = v;   // coalesced
    }
}

// ---------------------------------------------------------------------------
// GEMM1 v5: fp32 VALU, 256x128 block tile, 16x8 per thread, BK=32.
// v3's proven single-buffer 2-barrier structure (v4's dbuf cost occupancy
// and regressed). 48 KB LDS; A-tile = two packed 128-panels side by side.
// 128 FMA per 6 ds_read_b128 (2x v3's density); A-reads 4-addr broadcast.
// ---------------------------------------------------------------------------
__global__ __launch_bounds__(256, 2) void gemm1_v5(
    const float* __restrict__ Xp, const float* __restrict__ Wp,
    const float* __restrict__ b_ih, const float* __restrict__ b_hh,
    float* __restrict__ Z)
{
    __shared__ float Alds[32 * 256];   // 32 KB  word = k*256 + half*128 + pos
    __shared__ float Blds[32 * 128];   // 16 KB  word = k*128 + pos

    const int tid  = threadIdx.x;
    const int w    = tid >> 6;         // wave 0..3
    const int lane = tid & 63;
    const int tr   = tid >> 4;         // 0..15 -> rows tr*16..tr*16+15
    const int tc   = tid & 15;         // 0..15 -> cols tc*8..tc*8+7

    // XCD-bijective swizzle: 1600 = 8 * 200
    int bid   = blockIdx.x;
    int wg    = (bid & 7) * 200 + (bid >> 3);
    int mblk2 = wg >> 3;               // 0..199
    int nblk  = wg & 7;                // 0..7
    const int row0 = mblk2 * 256;
    const int col0 = nblk * 128;

    // A compute-read offsets: 4 granules of rows (tr&7)*16.. within half tr>>3
    const int ahalf = (tr >> 3) * 128;
    int aoff0 = ahalf + swz32((tr & 7) * 4 + 0) * 4;
    int aoff1 = ahalf + swz32((tr & 7) * 4 + 1) * 4;
    int aoff2 = ahalf + swz32((tr & 7) * 4 + 2) * 4;
    int aoff3 = ahalf + swz32((tr & 7) * 4 + 3) * 4;
    const int b0 = swz32(2 * tc)     * 4;
    const int b1 = swz32(2 * tc + 1) * 4;

    const float* pA0 = Xp + (size_t)(mblk2 * 2    ) * KT * TILE_WORDS;
    const float* pA1 = Xp + (size_t)(mblk2 * 2 + 1) * KT * TILE_WORDS;
    const float* pB  = Wp + (size_t)nblk * KT * TILE_WORDS;

    // A staging source: lane<32 -> panel0, lane>=32 -> panel1 (per-lane src OK;
    // dest stays wave-uniform-base + lane*16). k-row = 4*i + w.
    const float* aSrc = (lane < 32 ? pA0 : pA1) + w * 128 + (lane & 31) * 4;

    float acc[16][8] = {};

    for (int kt = 0; kt < KT; ++kt) {
        const float* aS = aSrc + kt * TILE_WORDS;
        const float* bS = pB + kt * TILE_WORDS + tid * 4;
        #pragma unroll
        for (int i = 0; i < 8; ++i)           // A: 32 KB
            gload16(aS + i * 512, &Alds[i * 1024 + tid * 4]);
        #pragma unroll
        for (int i = 0; i < 4; ++i)           // B: 16 KB
            gload16(bS + i * 1024, &Blds[i * 1024 + tid * 4]);
        __syncthreads();   // drains vmcnt(0): staged tile visible

        #pragma unroll 4
        for (int k = 0; k < 32; ++k) {
            const float* Ak = &Alds[k * 256];
            const float* Bk = &Blds[k * 128];
            const float4 A0 = *(const float4*)&Ak[aoff0];
            const float4 A1 = *(const float4*)&Ak[aoff1];
            const float4 A2 = *(const float4*)&Ak[aoff2];
            const float4 A3 = *(const float4*)&Ak[aoff3];
            const float4 B0 = *(const float4*)&Bk[b0];
            const float4 B1 = *(const float4*)&Bk[b1];
            #define FMA_ROW(i, av) \
                acc[i][0] = fmaf(av, B0.x, acc[i][0]); \
                acc[i][1] = fmaf(av, B0.y, acc[i][1]); \
                acc[i][2] = fmaf(av, B0.z, acc[i][2]); \
                acc[i][3] = fmaf(av, B0.w, acc[i][3]); \
                acc[i][4] = fmaf(av, B1.x, acc[i][4]); \
                acc[i][5] = fmaf(av, B1.y, acc[i][5]); \
                acc[i][6] = fmaf(av, B1.z, acc[i][6]); \
                acc[i][7] = fmaf(av, B1.w, acc[i][7]);
            FMA_ROW( 0, A0.x) FMA_ROW( 1, A0.y) FMA_ROW( 2, A0.z) FMA_ROW( 3, A0.w)
            FMA_ROW( 4, A1.x) FMA_ROW( 5, A1.y) FMA_ROW( 6, A1.z) FMA_ROW( 7, A1.w)
            FMA_ROW( 8, A2.x) FMA_ROW( 9, A2.y) FMA_ROW(10, A2.z) FMA_ROW(11, A2.w)
            FMA_ROW(12, A3.x) FMA_ROW(13, A3.y) FMA_ROW(14, A3.z) FMA_ROW(15, A3.w)
            #undef FMA_ROW
        }
        __syncthreads();   // all reads of this tile done before next stage
    }

    // ---- epilogue ----
    float bias[8];
    #pragma unroll
    for (int j = 0; j < 8; ++j) {
        int cc = col0 + tc * 8 + j;
        bias[j] = (cc < H_SZ) ? (b_ih[cc] + b_hh[cc]) : 0.f;
    }

    const bool full = (col0 + 127 < H_SZ);
    #pragma unroll
    for (int s = 0; s < 16; ++s) {
        int rr = row0 + tr * 16 + s;
        float* zrow = Z + (size_t)rr * H_SZ + col0 + tc * 8;
        if (full) {
            float4 v0 = make_float4(acc[s][0] + bias[0], acc[s][1] + bias[1],
                                    acc[s][2] + bias[2], acc[s][3] + bias[3]);
            float4 v1 = make_float4(acc[s][4] + bias[4], acc[s][5] + bias[5],
                                    acc[s][6] + bias[6], acc[s][7] + bias[7]);
            *(float4*)(zrow + 0) = v0;
            *(float4*)(zrow + 4) = v1;
        } else {
            #pragma unroll
            for (int j = 0; j < 8; ++j) {
                int cc = col0 + tc * 8 + j;
                if (cc < H_SZ) zrow[j] = acc[s][j] + bias[j];
            }
        }
    }
}

// ---------------------------------------------------------------------------
// Scan1: per (b,h) chain over t; in-place z1 -> spikes (0/1 as float).
// ---------------------------------------------------------------------------
__global__ __launch_bounds__(256) void scan1_kernel(
    float* __restrict__ Z, const float* __restrict__ beta)
{
    int idx = blockIdx.x * blockDim.x + threadIdx.x;
    if (idx >= B_SZ * H_SZ) return;
    int h = idx % H_SZ;
    float be = fminf(fmaxf(beta[h], 0.f), 1.f);
    float hm = 0.f;
    const size_t stride = (size_t)B_SZ * H_SZ;
    float* p = Z + idx;
    for (int t = 0; t < T_STEPS; ++t) {
        float v = p[(size_t)t * stride];
        hm = fmaxf(fmaf(be, hm, v), 0.f);
        p[(size_t)t * stride] = (hm > 1.0f) ? 1.0f : 0.0f;
    }
}

// ---------------------------------------------------------------------------
// GEMM2: one wave per row, W2 (40KB) in LDS. Writes directly to d_out.
// ---------------------------------------------------------------------------
__global__ __launch_bounds__(256) void gemm2_kernel(
    const float* __restrict__ S, const float* __restrict__ W2,
    const float* __restrict__ b_ih2, const float* __restrict__ b_hh2,
    float* __restrict__ Z2)
{
    __shared__ float W2s[O_SZ * H_SZ];
    for (int i = threadIdx.x; i < O_SZ * H_SZ; i += blockDim.x)
        W2s[i] = W2[i];
    __syncthreads();

    const int wave  = threadIdx.x >> 6;
    const int lane  = threadIdx.x & 63;
    const int wgid  = blockIdx.x * (blockDim.x >> 6) + wave;
    const int nwave = gridDim.x * (blockDim.x >> 6);

    for (int m = wgid; m < M_ROWS; m += nwave) {
        const float* row = S + (size_t)m * H_SZ;
        float acc[O_SZ];
        #pragma unroll
        for (int o = 0; o < O_SZ; ++o) acc[o] = 0.f;

        for (int h = lane; h < H_SZ; h += 64) {
            float s = row[h];
            #pragma unroll
            for (int o = 0; o < O_SZ; ++o)
                acc[o] = fmaf(s, W2s[o * H_SZ + h], acc[o]);
        }
        #pragma unroll
        for (int o = 0; o < O_SZ; ++o) {
            float v = acc[o];
            #pragma unroll
            for (int off = 32; off > 0; off >>= 1)
                v += __shfl_down(v, off, 64);
            if (lane == 0)
                Z2[(size_t)m * O_SZ + o] = v + b_ih2[o] + b_hh2[o];
        }
    }
}

// ---------------------------------------------------------------------------
// Scan2: in-place on d_out (thread-private read-then-write).
// ---------------------------------------------------------------------------
#define CH 20
__global__ __launch_bounds__(256) void scan2_kernel(
    float* __restrict__ Z2io, const float* __restrict__ beta2)
{
    int idx = blockIdx.x * blockDim.x + threadIdx.x;
    if (idx >= B_SZ * O_SZ) return;
    int o = idx % O_SZ;
    float be = fminf(fmaxf(beta2[o], 0.f), 1.f);
    float hm = 0.f;
    const int stride = B_SZ * O_SZ;
    for (int t0 = 0; t0 < T_STEPS; t0 += CH) {
        float v[CH];
        #pragma unroll
        for (int i = 0; i < CH; ++i)
            v[i] = Z2io[(size_t)(t0 + i) * stride + idx];
        #pragma unroll
        for (int i = 0; i < CH; ++i) {
            hm = fmaxf(fmaf(be, hm, v[i]), 0.f);
            Z2io[(size_t)(t0 + i) * stride + idx] = (hm > 1.0f) ? 1.0f : 0.0f;
        }
    }
}

// ---------------------------------------------------------------------------
extern "C" void kernel_launch(void* const* d_in, const int* in_sizes, int n_in,
                              void* d_out, int out_size, void* d_ws, size_t ws_size,
                              hipStream_t stream)
{
    const float* x     = (const float*)d_in[0];
    const float* W1    = (const float*)d_in[1];
    const float* bih1  = (const float*)d_in[2];
    const float* bhh1  = (const float*)d_in[3];
    const float* beta1 = (const float*)d_in[4];
    const float* W2    = (const float*)d_in[5];
    const float* bih2  = (const float*)d_in[6];
    const float* bhh2  = (const float*)d_in[7];
    const float* beta2 = (const float*)d_in[8];
    float* out = (float*)d_out;

    // workspace: z1 (204.8 MB) + Xp (163.84 MB) + Wp (3.28 MB) = 371.9 MB
    char* base = (char*)d_ws;
    float* z1 = (float*)base;
    float* Xp = (float*)(base + (size_t)M_ROWS * H_SZ * 4);
    float* Wp = Xp + (size_t)MBLKS * KT * TILE_WORDS;

    pack_kernel<<<MBLKS * KT, 256, 0, stream>>>(x,  Xp, M_ROWS);
    pack_kernel<<<NBLKS * KT, 256, 0, stream>>>(W1, Wp, H_SZ);

    gemm1_v5<<<MBLK2S * NBLKS, 256, 0, stream>>>(Xp, Wp, bih1, bhh1, z1);

    scan1_kernel<<<(B_SZ * H_SZ) / 256, 256, 0, stream>>>(z1, beta1);
    gemm2_kernel<<<2048, 256, 0, stream>>>(z1, W2, bih2, bhh2, out);
    scan2_kernel<<<(B_SZ * O_SZ + 255) / 256, 256, 0, stream>>>(out, beta2);
}